// Round 4
// baseline (212.885 us; speedup 1.0000x reference)
//
#include <hip/hip_runtime.h>
#include <hip/hip_bf16.h>

// ---------- Problem constants (fixed-shape problem) ----------
constexpr int Bsz = 2;
constexpr int L   = 2048;
constexpr int D   = 2048;
constexpr int Nst = 8;
constexpr int DM  = 1024;
constexpr int M   = Bsz * L;   // 4096 rows for all GEMMs

constexpr int CH  = 64;        // scan chunks
constexpr int T   = L / CH;    // 32 steps per chunk
constexpr int BDN = Bsz * D * Nst;

typedef __bf16 bf16x8 __attribute__((ext_vector_type(8)));
typedef float f32x4  __attribute__((ext_vector_type(4)));
typedef float f32x16 __attribute__((ext_vector_type(16)));

// ---------- float -> bf16 cast (for weights) ----------
__global__ void cvt_f32_bf16(const float* __restrict__ in, __bf16* __restrict__ out, int n4) {
    int i = blockIdx.x * blockDim.x + threadIdx.x;
    if (i >= n4) return;
    float4 v = reinterpret_cast<const float4*>(in)[i];
    union { __bf16 b[4]; ushort4 u; } cv;
    cv.b[0] = (__bf16)v.x; cv.b[1] = (__bf16)v.y; cv.b[2] = (__bf16)v.z; cv.b[3] = (__bf16)v.w;
    reinterpret_cast<ushort4*>(out)[i] = cv.u;
}

// ---------- x_dbl = x @ x_proj_w^T + b (f32 exact), fused x->bf16 emission ----------
__global__ __launch_bounds__(256) void xdbl_kernel(
    const float* __restrict__ x, const float* __restrict__ w,
    const float* __restrict__ bias, float* __restrict__ xdbl,
    __bf16* __restrict__ x_bf)
{
    __shared__ float sw[16 * 2048];          // 128 KB
    const int tid = threadIdx.x;
    for (int i = tid; i < 16 * 2048 / 4; i += 256)
        reinterpret_cast<float4*>(sw)[i] = reinterpret_cast<const float4*>(w)[i];
    __syncthreads();

    const int lane = tid & 63;
    const int wrow = tid >> 6;
    for (int rr = 0; rr < 4; ++rr) {
        const int row = blockIdx.x * 16 + wrow * 4 + rr;
        const float* xr = x + (size_t)row * D;
        __bf16* xb = x_bf + (size_t)row * D;
        float acc[16];
#pragma unroll
        for (int j = 0; j < 16; ++j) acc[j] = 0.f;
        for (int k = lane * 4; k < D; k += 256) {
            float4 xv = *reinterpret_cast<const float4*>(&xr[k]);
            union { __bf16 b[4]; ushort4 u; } cv;
            cv.b[0] = (__bf16)xv.x; cv.b[1] = (__bf16)xv.y;
            cv.b[2] = (__bf16)xv.z; cv.b[3] = (__bf16)xv.w;
            *reinterpret_cast<ushort4*>(&xb[k]) = cv.u;
#pragma unroll
            for (int j = 0; j < 16; ++j) {
                float4 wv = *reinterpret_cast<const float4*>(&sw[j * D + k]);
                acc[j] += xv.x * wv.x + xv.y * wv.y + xv.z * wv.z + xv.w * wv.w;
            }
        }
#pragma unroll
        for (int j = 0; j < 16; ++j) {
            float v = acc[j];
#pragma unroll
            for (int off = 32; off > 0; off >>= 1) v += __shfl_down(v, off, 64);
            if (lane == 0) xdbl[(size_t)row * 16 + j] = v + bias[j];
        }
    }
}

// ---------- async global->LDS 16B helper ----------
__device__ inline void async16(__bf16* lds, const __bf16* g) {
    __builtin_amdgcn_global_load_lds(
        (const __attribute__((address_space(1))) void*)g,
        (__attribute__((address_space(3))) void*)lds, 16, 0, 0);
}

// ---------- C[M,N] = A[M,Kfull] @ Bw[N,Kfull]^T (+ bias) ----------
// 128x128 tile, BK=64, double-buffered LDS, prefetch depth 2, counted vmcnt(8),
// T2 XOR swizzle (pre-swizzled global source + XOR'd ds_read), T5 setprio,
// 32x32x16 MFMA (wave tile 64x64 = 2x2 of 32x32).
// MODE 0: store acc+bias. MODE 1: store softplus(acc+bias).
// MODE 2: unsafeAtomicAdd(acc [+bias if z==0]) — split-K over gridDim.z.
template <int MODE>
__global__ __launch_bounds__(256, 2) void gemm_bt(
    const __bf16* __restrict__ A, const __bf16* __restrict__ Bw,
    const float* __restrict__ bias, float* __restrict__ C,
    int N, int Kfull, int Ksub)
{
    constexpr int BM = 128, BN = 128, BK = 64;
    const int NT  = Ksub / BK;
    const int zoff = blockIdx.z * Ksub;
    __shared__ __attribute__((aligned(16))) __bf16 lds[2][2][BM * BK];  // [buf][A/B]

    const int tid  = threadIdx.x;
    const int lane = tid & 63;
    const int wid  = tid >> 6;
    const int wm   = wid >> 1, wn = wid & 1;          // 2x2 waves, 64x64 each
    const int rowBase = blockIdx.y * BM;
    const int colBase = blockIdx.x * BN;
    const int l31   = lane & 31;
    const int khalf = lane >> 5;                      // 0/1
    const int l7    = lane & 7;

    // bias prefetch, then drain vmcnt so manual load counting below is exact
    float bv[2];
#pragma unroll
    for (int n = 0; n < 2; ++n) {
        bv[n] = bias[colBase + wn * 64 + n * 32 + l31];
        if (MODE == 2 && blockIdx.z != 0) bv[n] = 0.f;
    }
    asm volatile("s_waitcnt vmcnt(0)" ::: "memory");

    // staging: LDS dest linear; global source column pre-swizzled (same involution as reads)
    const int trow = tid >> 3;                        // row within 32-row round
    const int scol = ((tid & 7) ^ (trow & 7)) * 8;    // swizzled element col
    const __bf16* gA[4]; const __bf16* gB[4];
#pragma unroll
    for (int ro = 0; ro < 4; ++ro) {
        gA[ro] = A  + (size_t)(rowBase + ro * 32 + trow) * Kfull + zoff + scol;
        gB[ro] = Bw + (size_t)(colBase + ro * 32 + trow) * Kfull + zoff + scol;
    }

    f32x16 acc[2][2];
#pragma unroll
    for (int i = 0; i < 2; ++i)
#pragma unroll
        for (int j = 0; j < 2; ++j)
#pragma unroll
            for (int r = 0; r < 16; ++r) acc[i][j][r] = 0.f;

    auto stage = [&](int kt, int bsel) {              // 8 gload_lds / thread
        const int k0 = kt * BK;
#pragma unroll
        for (int ro = 0; ro < 4; ++ro) {
            async16(&lds[bsel][0][ro * 2048 + tid * 8], gA[ro] + k0);
            async16(&lds[bsel][1][ro * 2048 + tid * 8], gB[ro] + k0);
        }
    };

    stage(0, 0);
    stage(1, 1);

    for (int t = 0; t < NT; ++t) {
        if (t == NT - 1) asm volatile("s_waitcnt vmcnt(0)" ::: "memory");
        else             asm volatile("s_waitcnt vmcnt(8)" ::: "memory");
        __builtin_amdgcn_s_barrier();                 // tile t resident

        const int cur = t & 1;
        bf16x8 af[2][4], bfr[2][4];
#pragma unroll
        for (int m = 0; m < 2; ++m) {
            const int row = wm * 64 + m * 32 + l31;
#pragma unroll
            for (int ks = 0; ks < 4; ++ks) {
                const int slot = (ks * 2 + khalf) ^ l7;      // T2 read-side XOR
                af[m][ks] = *reinterpret_cast<const bf16x8*>(&lds[cur][0][row * 64 + slot * 8]);
            }
        }
#pragma unroll
        for (int n = 0; n < 2; ++n) {
            const int row = wn * 64 + n * 32 + l31;
#pragma unroll
            for (int ks = 0; ks < 4; ++ks) {
                const int slot = (ks * 2 + khalf) ^ l7;
                bfr[n][ks] = *reinterpret_cast<const bf16x8*>(&lds[cur][1][row * 64 + slot * 8]);
            }
        }
        asm volatile("s_waitcnt lgkmcnt(0)" ::: "memory");   // my reads sampled
        __builtin_amdgcn_sched_barrier(0);                   // rule #18 fence
        __builtin_amdgcn_s_barrier();                        // all waves done with buf[cur]

        if (t + 2 < NT) stage(t + 2, cur);                   // safe overwrite, flies under MFMA

        __builtin_amdgcn_s_setprio(1);
#pragma unroll
        for (int ks = 0; ks < 4; ++ks)
#pragma unroll
            for (int m = 0; m < 2; ++m)
#pragma unroll
                for (int n = 0; n < 2; ++n)
                    acc[m][n] = __builtin_amdgcn_mfma_f32_32x32x16_bf16(af[m][ks], bfr[n][ks], acc[m][n], 0, 0, 0);
        __builtin_amdgcn_s_setprio(0);
    }

    // epilogue: 32x32 C/D layout col = lane&31, row = (reg&3) + 8*(reg>>2) + 4*(lane>>5)
#pragma unroll
    for (int m = 0; m < 2; ++m) {
        const int rb = rowBase + wm * 64 + m * 32 + 4 * khalf;
#pragma unroll
        for (int n = 0; n < 2; ++n) {
            const int col = colBase + wn * 64 + n * 32 + l31;
#pragma unroll
            for (int r = 0; r < 16; ++r) {
                const int row = rb + (r & 3) + 8 * (r >> 2);
                float v = acc[m][n][r] + bv[n];
                if (MODE == 1) v = (v > 20.f) ? v : log1pf(expf(v));
                if (MODE == 2) unsafeAtomicAdd(&C[(size_t)row * N + col], v);
                else           C[(size_t)row * N + col] = v;
            }
        }
    }
}

// ================= chunk-parallel selective scan =================
__global__ __launch_bounds__(64) void scan_p1(
    const float* __restrict__ dt, const float* __restrict__ x,
    const float* __restrict__ xdbl, const float* __restrict__ A_log,
    float* __restrict__ P, float* __restrict__ Hloc)
{
    const int tid = threadIdx.x;
    int blk = blockIdx.x;
    const int c  = blk % CH;  blk /= CH;
    const int dg = blk % (D / 64);
    const int b  = blk / (D / 64);
    const int d  = dg * 64 + tid;

    float A[Nst], h[Nst], p[Nst];
#pragma unroll
    for (int n = 0; n < Nst; ++n) {
        A[n] = -expf(A_log[(size_t)d * Nst + n]);
        h[n] = 0.f; p[n] = 1.f;
    }

    __shared__ __attribute__((aligned(16))) float sBC[T * 16];
    const float4* src = reinterpret_cast<const float4*>(xdbl + ((size_t)b * L + c * T) * 16);
#pragma unroll
    for (int i = tid; i < T * 4; i += 64)
        reinterpret_cast<float4*>(sBC)[i] = src[i];
    __syncthreads();

    const float* dt_p = dt + ((size_t)b * L + c * T) * D + d;
    const float* x_p  = x  + ((size_t)b * L + c * T) * D + d;
#pragma unroll 4
    for (int t2 = 0; t2 < T; ++t2) {
        const float dtv = dt_p[(size_t)t2 * D];
        const float xv  = x_p[(size_t)t2 * D];
        const float dtx = dtv * xv;
        const float* bc = &sBC[t2 * 16];
#pragma unroll
        for (int n = 0; n < Nst; ++n) {
            const float dA = __expf(dtv * A[n]);
            p[n] *= dA;
            h[n] = dA * h[n] + dtx * bc[n];
        }
    }
    const size_t base = ((size_t)c * Bsz * D + (size_t)b * D + d) * Nst;
#pragma unroll
    for (int n = 0; n < Nst; ++n) { P[base + n] = p[n]; Hloc[base + n] = h[n]; }
}

__global__ __launch_bounds__(256) void scan_p2(
    const float* __restrict__ P, const float* __restrict__ Hloc,
    float* __restrict__ Hstart)
{
    const int id = blockIdx.x * blockDim.x + threadIdx.x;
    if (id >= BDN) return;
    float h = 0.f;
    for (int c = 0; c < CH; ++c) {
        const size_t o = (size_t)c * BDN + id;
        Hstart[o] = h;
        h = P[o] * h + Hloc[o];
    }
}

__global__ __launch_bounds__(64) void scan_p3(
    const float* __restrict__ dt, const float* __restrict__ x,
    const float* __restrict__ xdbl, const float* __restrict__ A_log,
    const float* __restrict__ Hstart, __bf16* __restrict__ y_bf)
{
    const int tid = threadIdx.x;
    int blk = blockIdx.x;
    const int c  = blk % CH;  blk /= CH;
    const int dg = blk % (D / 64);
    const int b  = blk / (D / 64);
    const int d  = dg * 64 + tid;

    float A[Nst], h[Nst];
    const size_t hbase = ((size_t)c * Bsz * D + (size_t)b * D + d) * Nst;
#pragma unroll
    for (int n = 0; n < Nst; ++n) {
        A[n] = -expf(A_log[(size_t)d * Nst + n]);
        h[n] = Hstart[hbase + n];
    }

    __shared__ __attribute__((aligned(16))) float sBC[T * 16];
    const float4* src = reinterpret_cast<const float4*>(xdbl + ((size_t)b * L + c * T) * 16);
#pragma unroll
    for (int i = tid; i < T * 4; i += 64)
        reinterpret_cast<float4*>(sBC)[i] = src[i];
    __syncthreads();

    const float* dt_p = dt + ((size_t)b * L + c * T) * D + d;
    const float* x_p  = x  + ((size_t)b * L + c * T) * D + d;
    __bf16*      y_p  = y_bf + ((size_t)b * L + c * T) * D + d;
#pragma unroll 4
    for (int t2 = 0; t2 < T; ++t2) {
        const float dtv = dt_p[(size_t)t2 * D];
        const float xv  = x_p[(size_t)t2 * D];
        const float dtx = dtv * xv;
        const float* bc = &sBC[t2 * 16];
        float y = 0.f;
#pragma unroll
        for (int n = 0; n < Nst; ++n) {
            const float dA = __expf(dtv * A[n]);
            h[n] = dA * h[n] + dtx * bc[n];
            y = fmaf(h[n], bc[8 + n], y);
        }
        y_p[(size_t)t2 * D] = (__bf16)y;
    }
}

extern "C" void kernel_launch(void* const* d_in, const int* in_sizes, int n_in,
                              void* d_out, int out_size, void* d_ws, size_t ws_size,
                              hipStream_t stream) {
    const float* x     = (const float*)d_in[0];
    const float* A_log = (const float*)d_in[1];
    const float* xpw   = (const float*)d_in[2];
    const float* xpb   = (const float*)d_in[3];
    const float* dtw   = (const float*)d_in[4];
    const float* dtb   = (const float*)d_in[5];
    const float* ow    = (const float*)d_in[6];
    const float* ob    = (const float*)d_in[7];
    float* out = (float*)d_out;

    char* ws = (char*)d_ws;
    __bf16* x_bf   = (__bf16*)(ws);                 // 16,777,216 B (dead after dt-GEMM)
    __bf16* dtw_bf = (__bf16*)(ws + 16777216);      //  8,388,608 B (dead after dt-GEMM)
    __bf16* ow_bf  = (__bf16*)(ws + 25165824);      //  4,194,304 B (live until out-GEMM)
    float*  xdbl   = (float* )(ws + 29360128);      //    262,144 B
    float*  dtbuf  = (float* )(ws + 29622272);      // 33,554,432 B
    __bf16* y_bf   = (__bf16*)(ws + 63176704);      // 16,777,216 B
    // scan scratch overlays the dead bf16 operand copies:
    float*  P      = (float*)(ws);                  // over x_bf lo
    float*  Hloc   = (float*)(ws + 8388608);        // over x_bf hi
    float*  Hstart = (float*)(ws + 16777216);       // over dtw_bf

    // 1) bf16 weight copies
    cvt_f32_bf16<<<(D * D / 4 + 255) / 256, 256, 0, stream>>>(dtw, dtw_bf, D * D / 4);
    cvt_f32_bf16<<<(DM * D / 4 + 255) / 256, 256, 0, stream>>>(ow, ow_bf, DM * D / 4);

    // 2) B_t / C_t gates (exact f32) + fused x->bf16 emission
    xdbl_kernel<<<M / 16, 256, 0, stream>>>(x, xpw, xpb, xdbl, x_bf);

    // 3) dt = softplus(x @ dtw^T + dtb)
    gemm_bt<1><<<dim3(D / 128, M / 128, 1), 256, 0, stream>>>(x_bf, dtw_bf, dtb, dtbuf, D, D, D);

    // 4) chunk-parallel selective scan -> y (bf16)
    const int scan_blocks = Bsz * (D / 64) * CH;    // 4096
    scan_p1<<<scan_blocks, 64, 0, stream>>>(dtbuf, x, xdbl, A_log, P, Hloc);
    scan_p2<<<(BDN + 255) / 256, 256, 0, stream>>>(P, Hloc, Hstart);
    scan_p3<<<scan_blocks, 64, 0, stream>>>(dtbuf, x, xdbl, A_log, Hstart, y_bf);

    // 5) out = y @ ow^T + ob   — split-K=2, atomic accumulate into zeroed out
    hipMemsetAsync(out, 0, (size_t)out_size * sizeof(float), stream);
    gemm_bt<2><<<dim3(DM / 128, M / 128, 2), 256, 0, stream>>>(y_bf, ow_bf, ob, out, DM, D, D / 2);
}

// Round 5
// 197.157 us; speedup vs baseline: 1.0798x; 1.0798x over previous
//
#include <hip/hip_runtime.h>
#include <hip/hip_bf16.h>

// ---------- Problem constants (fixed-shape problem) ----------
constexpr int Bsz = 2;
constexpr int L   = 2048;
constexpr int D   = 2048;
constexpr int Nst = 8;
constexpr int DM  = 1024;
constexpr int M   = Bsz * L;   // 4096 rows for all GEMMs

constexpr int CH  = 64;        // scan chunks
constexpr int T   = L / CH;    // 32 steps per chunk
constexpr int BDN = Bsz * D * Nst;

typedef __bf16 bf16x8 __attribute__((ext_vector_type(8)));
typedef float f32x4  __attribute__((ext_vector_type(4)));

// ---------- float -> bf16 cast (for weights) ----------
__global__ void cvt_f32_bf16(const float* __restrict__ in, __bf16* __restrict__ out, int n4) {
    int i = blockIdx.x * blockDim.x + threadIdx.x;
    if (i >= n4) return;
    float4 v = reinterpret_cast<const float4*>(in)[i];
    union { __bf16 b[4]; ushort4 u; } cv;
    cv.b[0] = (__bf16)v.x; cv.b[1] = (__bf16)v.y; cv.b[2] = (__bf16)v.z; cv.b[3] = (__bf16)v.w;
    reinterpret_cast<ushort4*>(out)[i] = cv.u;
}

// ---------- x_dbl = x @ x_proj_w^T + b (f32 exact), fused x->bf16 emission ----------
__global__ __launch_bounds__(256) void xdbl_kernel(
    const float* __restrict__ x, const float* __restrict__ w,
    const float* __restrict__ bias, float* __restrict__ xdbl,
    __bf16* __restrict__ x_bf)
{
    __shared__ float sw[16 * 2048];          // 128 KB
    const int tid = threadIdx.x;
    for (int i = tid; i < 16 * 2048 / 4; i += 256)
        reinterpret_cast<float4*>(sw)[i] = reinterpret_cast<const float4*>(w)[i];
    __syncthreads();

    const int lane = tid & 63;
    const int wrow = tid >> 6;
    for (int rr = 0; rr < 4; ++rr) {
        const int row = blockIdx.x * 16 + wrow * 4 + rr;
        const float* xr = x + (size_t)row * D;
        __bf16* xb = x_bf + (size_t)row * D;
        float acc[16];
#pragma unroll
        for (int j = 0; j < 16; ++j) acc[j] = 0.f;
        for (int k = lane * 4; k < D; k += 256) {
            float4 xv = *reinterpret_cast<const float4*>(&xr[k]);
            union { __bf16 b[4]; ushort4 u; } cv;
            cv.b[0] = (__bf16)xv.x; cv.b[1] = (__bf16)xv.y;
            cv.b[2] = (__bf16)xv.z; cv.b[3] = (__bf16)xv.w;
            *reinterpret_cast<ushort4*>(&xb[k]) = cv.u;
#pragma unroll
            for (int j = 0; j < 16; ++j) {
                float4 wv = *reinterpret_cast<const float4*>(&sw[j * D + k]);
                acc[j] += xv.x * wv.x + xv.y * wv.y + xv.z * wv.z + xv.w * wv.w;
            }
        }
#pragma unroll
        for (int j = 0; j < 16; ++j) {
            float v = acc[j];
#pragma unroll
            for (int off = 32; off > 0; off >>= 1) v += __shfl_down(v, off, 64);
            if (lane == 0) xdbl[(size_t)row * 16 + j] = v + bias[j];
        }
    }
}

// ---------- async global->LDS 16B helper ----------
__device__ inline void async16(__bf16* lds, const __bf16* g) {
    __builtin_amdgcn_global_load_lds(
        (const __attribute__((address_space(1))) void*)g,
        (__attribute__((address_space(3))) void*)lds, 16, 0, 0);
}

// ---------- C[M,N] = A[M,Kfull] @ Bw[N,Kfull]^T (+ bias) ----------
// R3-verified structure: 128x128 tile, BK=64, double-buffered LDS, prefetch
// depth 2, counted vmcnt(8), T2 XOR swizzle (0-conflict 16x16 read geometry),
// T5 setprio, 16x16x32 MFMA.
// MODE 0: store acc+bias.  MODE 1: store softplus(acc+bias).
// MODE 3: split-K partial — store raw acc (no bias) at C + z*M*N.
// SWZ 1: XCD-aware block swizzle (requires gridDim.x*gridDim.y % 8 == 0).
template <int MODE, int SWZ>
__global__ __launch_bounds__(256, 2) void gemm_bt(
    const __bf16* __restrict__ A, const __bf16* __restrict__ Bw,
    const float* __restrict__ bias, float* __restrict__ C,
    int N, int Kfull, int Ksub)
{
    constexpr int BM = 128, BN = 128, BK = 64;
    const int NT  = Ksub / BK;
    const int zoff = blockIdx.z * Ksub;
    __shared__ __attribute__((aligned(16))) __bf16 lds[2][2][BM * BK];  // [buf][A/B]

    int bx = blockIdx.x, by = blockIdx.y;
    if (SWZ) {                                        // T1: contiguous chunk per XCD
        const int lin = by * gridDim.x + bx;
        const int cpx = (gridDim.x * gridDim.y) >> 3;
        const int swz = (lin & 7) * cpx + (lin >> 3);
        bx = swz % gridDim.x; by = swz / gridDim.x;
    }

    const int tid  = threadIdx.x;
    const int lane = tid & 63;
    const int wid  = tid >> 6;
    const int wm   = wid >> 1, wn = wid & 1;          // 2x2 waves, 64x64 each
    const int rowBase = by * BM;
    const int colBase = bx * BN;
    const int lrow = lane & 15;
    const int kgrp = lane >> 4;

    // bias prefetch, then drain vmcnt so manual load counting below is exact
    float bv[4];
#pragma unroll
    for (int n = 0; n < 4; ++n)
        bv[n] = (MODE == 3) ? 0.f : bias[colBase + wn * 64 + n * 16 + lrow];
    asm volatile("s_waitcnt vmcnt(0)" ::: "memory");

    // staging: LDS dest linear; global source column pre-swizzled (same involution as reads)
    const int trow = tid >> 3;                        // row within 32-row round
    const int scol = ((tid & 7) ^ (trow & 7)) * 8;    // swizzled element col
    const __bf16* gA[4]; const __bf16* gB[4];
#pragma unroll
    for (int ro = 0; ro < 4; ++ro) {
        gA[ro] = A  + (size_t)(rowBase + ro * 32 + trow) * Kfull + zoff + scol;
        gB[ro] = Bw + (size_t)(colBase + ro * 32 + trow) * Kfull + zoff + scol;
    }

    f32x4 acc[4][4];
#pragma unroll
    for (int i = 0; i < 4; ++i)
#pragma unroll
        for (int j = 0; j < 4; ++j) acc[i][j] = f32x4{0.f, 0.f, 0.f, 0.f};

    auto stage = [&](int kt, int bsel) {              // 8 gload_lds / thread
        const int k0 = kt * BK;
#pragma unroll
        for (int ro = 0; ro < 4; ++ro) {
            async16(&lds[bsel][0][ro * 2048 + tid * 8], gA[ro] + k0);
            async16(&lds[bsel][1][ro * 2048 + tid * 8], gB[ro] + k0);
        }
    };

    stage(0, 0);
    stage(1, 1);

    for (int t = 0; t < NT; ++t) {
        if (t == NT - 1) asm volatile("s_waitcnt vmcnt(0)" ::: "memory");
        else             asm volatile("s_waitcnt vmcnt(8)" ::: "memory");
        __builtin_amdgcn_s_barrier();                 // tile t resident

        const int cur = t & 1;
        bf16x8 af[4][2], bfr[4][2];
#pragma unroll
        for (int m = 0; m < 4; ++m) {
            const int row = wm * 64 + m * 16 + lrow;
#pragma unroll
            for (int kk = 0; kk < 2; ++kk) {
                const int slot = (kk * 4 + kgrp) ^ (lrow & 7);   // 0-conflict involution (R3)
                af[m][kk] = *reinterpret_cast<const bf16x8*>(&lds[cur][0][row * 64 + slot * 8]);
            }
        }
#pragma unroll
        for (int n = 0; n < 4; ++n) {
            const int row = wn * 64 + n * 16 + lrow;
#pragma unroll
            for (int kk = 0; kk < 2; ++kk) {
                const int slot = (kk * 4 + kgrp) ^ (lrow & 7);
                bfr[n][kk] = *reinterpret_cast<const bf16x8*>(&lds[cur][1][row * 64 + slot * 8]);
            }
        }
        asm volatile("s_waitcnt lgkmcnt(0)" ::: "memory");   // my reads sampled
        __builtin_amdgcn_sched_barrier(0);                   // rule #18 fence
        __builtin_amdgcn_s_barrier();                        // all waves done with buf[cur]

        if (t + 2 < NT) stage(t + 2, cur);                   // safe overwrite, flies under MFMA

        __builtin_amdgcn_s_setprio(1);
#pragma unroll
        for (int kk = 0; kk < 2; ++kk)
#pragma unroll
            for (int m = 0; m < 4; ++m)
#pragma unroll
                for (int n = 0; n < 4; ++n)
                    acc[m][n] = __builtin_amdgcn_mfma_f32_16x16x32_bf16(af[m][kk], bfr[n][kk], acc[m][n], 0, 0, 0);
        __builtin_amdgcn_s_setprio(0);
    }

    // epilogue: C/D layout col = lane&15, row = (lane>>4)*4 + reg
    float* Cz = (MODE == 3) ? C + (size_t)blockIdx.z * M * N : C;
#pragma unroll
    for (int m = 0; m < 4; ++m) {
        const int row = rowBase + wm * 64 + m * 16 + kgrp * 4;
#pragma unroll
        for (int n = 0; n < 4; ++n) {
            const int col = colBase + wn * 64 + n * 16 + lrow;
#pragma unroll
            for (int r = 0; r < 4; ++r) {
                float v = acc[m][n][r] + bv[n];
                if (MODE == 1) v = (v > 20.f) ? v : log1pf(expf(v));
                Cz[(size_t)(row + r) * N + col] = v;
            }
        }
    }
}

// ---------- out = part0 + part1 + bias (split-K reduce) ----------
__global__ __launch_bounds__(256) void reduce_bias(
    const float* __restrict__ part, const float* __restrict__ bias,
    float* __restrict__ out)
{
    const int i = blockIdx.x * blockDim.x + threadIdx.x;     // float4 index
    const int n4 = M * DM / 4;
    if (i >= n4) return;
    float4 a = reinterpret_cast<const float4*>(part)[i];
    float4 b = reinterpret_cast<const float4*>(part + (size_t)M * DM)[i];
    float4 bb = *reinterpret_cast<const float4*>(&bias[(i * 4) % DM]);
    float4 r;
    r.x = a.x + b.x + bb.x; r.y = a.y + b.y + bb.y;
    r.z = a.z + b.z + bb.z; r.w = a.w + b.w + bb.w;
    reinterpret_cast<float4*>(out)[i] = r;
}

// ================= chunk-parallel selective scan =================
__global__ __launch_bounds__(64) void scan_p1(
    const float* __restrict__ dt, const float* __restrict__ x,
    const float* __restrict__ xdbl, const float* __restrict__ A_log,
    float* __restrict__ P, float* __restrict__ Hloc)
{
    const int tid = threadIdx.x;
    int blk = blockIdx.x;
    const int c  = blk % CH;  blk /= CH;
    const int dg = blk % (D / 64);
    const int b  = blk / (D / 64);
    const int d  = dg * 64 + tid;

    float A[Nst], h[Nst], p[Nst];
#pragma unroll
    for (int n = 0; n < Nst; ++n) {
        A[n] = -expf(A_log[(size_t)d * Nst + n]);
        h[n] = 0.f; p[n] = 1.f;
    }

    __shared__ __attribute__((aligned(16))) float sBC[T * 16];
    const float4* src = reinterpret_cast<const float4*>(xdbl + ((size_t)b * L + c * T) * 16);
#pragma unroll
    for (int i = tid; i < T * 4; i += 64)
        reinterpret_cast<float4*>(sBC)[i] = src[i];
    __syncthreads();

    const float* dt_p = dt + ((size_t)b * L + c * T) * D + d;
    const float* x_p  = x  + ((size_t)b * L + c * T) * D + d;
#pragma unroll 4
    for (int t2 = 0; t2 < T; ++t2) {
        const float dtv = dt_p[(size_t)t2 * D];
        const float xv  = x_p[(size_t)t2 * D];
        const float dtx = dtv * xv;
        const float* bc = &sBC[t2 * 16];
#pragma unroll
        for (int n = 0; n < Nst; ++n) {
            const float dA = __expf(dtv * A[n]);
            p[n] *= dA;
            h[n] = dA * h[n] + dtx * bc[n];
        }
    }
    const size_t base = ((size_t)c * Bsz * D + (size_t)b * D + d) * Nst;
#pragma unroll
    for (int n = 0; n < Nst; ++n) { P[base + n] = p[n]; Hloc[base + n] = h[n]; }
}

__global__ __launch_bounds__(256) void scan_p2(
    const float* __restrict__ P, const float* __restrict__ Hloc,
    float* __restrict__ Hstart)
{
    const int id = blockIdx.x * blockDim.x + threadIdx.x;
    if (id >= BDN) return;
    float h = 0.f;
    for (int c = 0; c < CH; ++c) {
        const size_t o = (size_t)c * BDN + id;
        Hstart[o] = h;
        h = P[o] * h + Hloc[o];
    }
}

__global__ __launch_bounds__(64) void scan_p3(
    const float* __restrict__ dt, const float* __restrict__ x,
    const float* __restrict__ xdbl, const float* __restrict__ A_log,
    const float* __restrict__ Hstart, __bf16* __restrict__ y_bf)
{
    const int tid = threadIdx.x;
    int blk = blockIdx.x;
    const int c  = blk % CH;  blk /= CH;
    const int dg = blk % (D / 64);
    const int b  = blk / (D / 64);
    const int d  = dg * 64 + tid;

    float A[Nst], h[Nst];
    const size_t hbase = ((size_t)c * Bsz * D + (size_t)b * D + d) * Nst;
#pragma unroll
    for (int n = 0; n < Nst; ++n) {
        A[n] = -expf(A_log[(size_t)d * Nst + n]);
        h[n] = Hstart[hbase + n];
    }

    __shared__ __attribute__((aligned(16))) float sBC[T * 16];
    const float4* src = reinterpret_cast<const float4*>(xdbl + ((size_t)b * L + c * T) * 16);
#pragma unroll
    for (int i = tid; i < T * 4; i += 64)
        reinterpret_cast<float4*>(sBC)[i] = src[i];
    __syncthreads();

    const float* dt_p = dt + ((size_t)b * L + c * T) * D + d;
    const float* x_p  = x  + ((size_t)b * L + c * T) * D + d;
    __bf16*      y_p  = y_bf + ((size_t)b * L + c * T) * D + d;
#pragma unroll 4
    for (int t2 = 0; t2 < T; ++t2) {
        const float dtv = dt_p[(size_t)t2 * D];
        const float xv  = x_p[(size_t)t2 * D];
        const float dtx = dtv * xv;
        const float* bc = &sBC[t2 * 16];
        float y = 0.f;
#pragma unroll
        for (int n = 0; n < Nst; ++n) {
            const float dA = __expf(dtv * A[n]);
            h[n] = dA * h[n] + dtx * bc[n];
            y = fmaf(h[n], bc[8 + n], y);
        }
        y_p[(size_t)t2 * D] = (__bf16)y;
    }
}

extern "C" void kernel_launch(void* const* d_in, const int* in_sizes, int n_in,
                              void* d_out, int out_size, void* d_ws, size_t ws_size,
                              hipStream_t stream) {
    const float* x     = (const float*)d_in[0];
    const float* A_log = (const float*)d_in[1];
    const float* xpw   = (const float*)d_in[2];
    const float* xpb   = (const float*)d_in[3];
    const float* dtw   = (const float*)d_in[4];
    const float* dtb   = (const float*)d_in[5];
    const float* ow    = (const float*)d_in[6];
    const float* ob    = (const float*)d_in[7];
    float* out = (float*)d_out;

    char* ws = (char*)d_ws;
    __bf16* x_bf   = (__bf16*)(ws);                 // 16,777,216 B (dead after dt-GEMM)
    __bf16* dtw_bf = (__bf16*)(ws + 16777216);      //  8,388,608 B (dead after dt-GEMM)
    __bf16* ow_bf  = (__bf16*)(ws + 25165824);      //  4,194,304 B (live until out-GEMM)
    float*  xdbl   = (float* )(ws + 29360128);      //    262,144 B
    float*  dtbuf  = (float* )(ws + 29622272);      // 33,554,432 B (dead after scan_p3)
    __bf16* y_bf   = (__bf16*)(ws + 63176704);      // 16,777,216 B
    // scan scratch overlays the dead bf16 operand copies:
    float*  P      = (float*)(ws);                  // over x_bf lo
    float*  Hloc   = (float*)(ws + 8388608);        // over x_bf hi
    float*  Hstart = (float*)(ws + 16777216);       // over dtw_bf
    // split-K partials overlay dead dtbuf (2 * 16 MB = 32 MB <= 33.5 MB):
    float*  Cpart  = (float*)(ws + 29622272);

    // 1) bf16 weight copies
    cvt_f32_bf16<<<(D * D / 4 + 255) / 256, 256, 0, stream>>>(dtw, dtw_bf, D * D / 4);
    cvt_f32_bf16<<<(DM * D / 4 + 255) / 256, 256, 0, stream>>>(ow, ow_bf, DM * D / 4);

    // 2) B_t / C_t gates (exact f32) + fused x->bf16 emission
    xdbl_kernel<<<M / 16, 256, 0, stream>>>(x, xpw, xpb, xdbl, x_bf);

    // 3) dt = softplus(x @ dtw^T + dtb)   — XCD-swizzled
    gemm_bt<1, 1><<<dim3(D / 128, M / 128, 1), 256, 0, stream>>>(x_bf, dtw_bf, dtb, dtbuf, D, D, D);

    // 4) chunk-parallel selective scan -> y (bf16)
    const int scan_blocks = Bsz * (D / 64) * CH;    // 4096
    scan_p1<<<scan_blocks, 64, 0, stream>>>(dtbuf, x, xdbl, A_log, P, Hloc);
    scan_p2<<<(BDN + 255) / 256, 256, 0, stream>>>(P, Hloc, Hstart);
    scan_p3<<<scan_blocks, 64, 0, stream>>>(dtbuf, x, xdbl, A_log, Hstart, y_bf);

    // 5) out = y @ ow^T + ob — split-K=2 partials (no atomics) + reduce
    gemm_bt<3, 0><<<dim3(DM / 128, M / 128, 2), 256, 0, stream>>>(y_bf, ow_bf, ob, Cpart, DM, D, D / 2);
    reduce_bias<<<(M * DM / 4 + 255) / 256, 256, 0, stream>>>(Cpart, ob, out);
}

// Round 6
// 186.210 us; speedup vs baseline: 1.1433x; 1.0588x over previous
//
#include <hip/hip_runtime.h>
#include <hip/hip_bf16.h>

// ---------- Problem constants (fixed-shape problem) ----------
constexpr int Bsz = 2;
constexpr int L   = 2048;
constexpr int D   = 2048;
constexpr int Nst = 8;
constexpr int DM  = 1024;
constexpr int M   = Bsz * L;   // 4096 rows for all GEMMs

constexpr int CH  = 64;        // scan chunks
constexpr int T   = L / CH;    // 32 steps per chunk
constexpr int BDN = Bsz * D * Nst;

typedef __bf16 bf16x8 __attribute__((ext_vector_type(8)));
typedef float f32x4  __attribute__((ext_vector_type(4)));

// ---------- two-buffer float -> bf16 cast (weights, fused launch) ----------
__global__ void cvt2_f32_bf16(const float* __restrict__ a, __bf16* __restrict__ oa, int n4a,
                              const float* __restrict__ b, __bf16* __restrict__ ob, int n4b) {
    int i = blockIdx.x * blockDim.x + threadIdx.x;
    const float* src; __bf16* dst; int j;
    if (i < n4a)            { src = a; dst = oa; j = i; }
    else if (i < n4a + n4b) { src = b; dst = ob; j = i - n4a; }
    else return;
    float4 v = reinterpret_cast<const float4*>(src)[j];
    union { __bf16 bb[4]; ushort4 u; } cv;
    cv.bb[0] = (__bf16)v.x; cv.bb[1] = (__bf16)v.y; cv.bb[2] = (__bf16)v.z; cv.bb[3] = (__bf16)v.w;
    reinterpret_cast<ushort4*>(dst)[j] = cv.u;
}

// ---------- x_dbl = x @ x_proj_w^T + b (f32 exact), fused x->bf16 emission ----------
__global__ __launch_bounds__(256) void xdbl_kernel(
    const float* __restrict__ x, const float* __restrict__ w,
    const float* __restrict__ bias, float* __restrict__ xdbl,
    __bf16* __restrict__ x_bf)
{
    __shared__ float sw[16 * 2048];          // 128 KB
    const int tid = threadIdx.x;
    for (int i = tid; i < 16 * 2048 / 4; i += 256)
        reinterpret_cast<float4*>(sw)[i] = reinterpret_cast<const float4*>(w)[i];
    __syncthreads();

    const int lane = tid & 63;
    const int wrow = tid >> 6;
    for (int rr = 0; rr < 4; ++rr) {
        const int row = blockIdx.x * 16 + wrow * 4 + rr;
        const float* xr = x + (size_t)row * D;
        __bf16* xb = x_bf + (size_t)row * D;
        float acc[16];
#pragma unroll
        for (int j = 0; j < 16; ++j) acc[j] = 0.f;
        for (int k = lane * 4; k < D; k += 256) {
            float4 xv = *reinterpret_cast<const float4*>(&xr[k]);
            union { __bf16 b[4]; ushort4 u; } cv;
            cv.b[0] = (__bf16)xv.x; cv.b[1] = (__bf16)xv.y;
            cv.b[2] = (__bf16)xv.z; cv.b[3] = (__bf16)xv.w;
            *reinterpret_cast<ushort4*>(&xb[k]) = cv.u;
#pragma unroll
            for (int j = 0; j < 16; ++j) {
                float4 wv = *reinterpret_cast<const float4*>(&sw[j * D + k]);
                acc[j] += xv.x * wv.x + xv.y * wv.y + xv.z * wv.z + xv.w * wv.w;
            }
        }
#pragma unroll
        for (int j = 0; j < 16; ++j) {
            float v = acc[j];
#pragma unroll
            for (int off = 32; off > 0; off >>= 1) v += __shfl_down(v, off, 64);
            if (lane == 0) xdbl[(size_t)row * 16 + j] = v + bias[j];
        }
    }
}

// ---------- async global->LDS 16B helper ----------
__device__ inline void async16(__bf16* lds, const __bf16* g) {
    __builtin_amdgcn_global_load_lds(
        (const __attribute__((address_space(1))) void*)g,
        (__attribute__((address_space(3))) void*)lds, 16, 0, 0);
}

// ---------- C[M,N] = A[M,Kfull] @ Bw[N,Kfull]^T (+ bias) ----------
// 128x128 tile, BK=64, 512 threads = 8 waves (2x4 grid, per-wave 64x32),
// double-buffered LDS, prefetch depth 2, counted vmcnt(4), T2 XOR swizzle
// (0-conflict 16x16 read geometry), T5 setprio. Scheduler UN-pinned
// (no sched_barrier(0) — plain-load lgkmcnt is compiler-tracked).
// MODE 0: store acc+bias.  MODE 1: store softplus(acc+bias).
// MODE 3: split-K partial — store raw acc (no bias) at C + z*M*N.
// SWZ 1: XCD-aware block swizzle (requires gridDim.x*gridDim.y % 8 == 0).
template <int MODE, int SWZ>
__global__ __launch_bounds__(512, 4) void gemm_bt(
    const __bf16* __restrict__ A, const __bf16* __restrict__ Bw,
    const float* __restrict__ bias, float* __restrict__ C,
    int N, int Kfull, int Ksub)
{
    constexpr int BM = 128, BN = 128, BK = 64;
    const int NT  = Ksub / BK;
    const int zoff = blockIdx.z * Ksub;
    __shared__ __attribute__((aligned(16))) __bf16 lds[2][2][BM * BK];  // [buf][A/B], 64 KiB

    int bx = blockIdx.x, by = blockIdx.y;
    if (SWZ) {                                        // T1: contiguous chunk per XCD
        const int lin = by * gridDim.x + bx;
        const int cpx = (gridDim.x * gridDim.y) >> 3;
        const int swz = (lin & 7) * cpx + (lin >> 3);
        bx = swz % gridDim.x; by = swz / gridDim.x;
    }

    const int tid  = threadIdx.x;
    const int lane = tid & 63;
    const int wid  = tid >> 6;                        // 8 waves
    const int wm   = wid >> 2, wn = wid & 3;          // 2x4: per-wave 64 rows x 32 cols
    const int rowBase = by * BM;
    const int colBase = bx * BN;
    const int lrow = lane & 15;
    const int kgrp = lane >> 4;

    // bias prefetch, then drain vmcnt so manual load counting below is exact
    float bv[2];
#pragma unroll
    for (int n = 0; n < 2; ++n)
        bv[n] = (MODE == 3) ? 0.f : bias[colBase + wn * 32 + n * 16 + lrow];
    asm volatile("s_waitcnt vmcnt(0)" ::: "memory");

    // staging: LDS dest linear; global source column pre-swizzled (same involution as reads)
    const int trow = tid >> 3;                        // row within 64-row round
    const int scol = ((tid & 7) ^ (trow & 7)) * 8;    // swizzled element col
    const __bf16* gA[2]; const __bf16* gB[2];
#pragma unroll
    for (int ro = 0; ro < 2; ++ro) {
        gA[ro] = A  + (size_t)(rowBase + ro * 64 + trow) * Kfull + zoff + scol;
        gB[ro] = Bw + (size_t)(colBase + ro * 64 + trow) * Kfull + zoff + scol;
    }

    f32x4 acc[4][2];
#pragma unroll
    for (int i = 0; i < 4; ++i)
#pragma unroll
        for (int j = 0; j < 2; ++j) acc[i][j] = f32x4{0.f, 0.f, 0.f, 0.f};

    auto stage = [&](int kt, int bsel) {              // 4 gload_lds / thread
        const int k0 = kt * BK;
#pragma unroll
        for (int ro = 0; ro < 2; ++ro) {
            async16(&lds[bsel][0][ro * 4096 + tid * 8], gA[ro] + k0);
            async16(&lds[bsel][1][ro * 4096 + tid * 8], gB[ro] + k0);
        }
    };

    stage(0, 0);
    stage(1, 1);

    for (int t = 0; t < NT; ++t) {
        // tile t's 4 loads retired; tile t+1's 4 stay in flight (never 0 mid-loop)
        if (t == NT - 1) asm volatile("s_waitcnt vmcnt(0)" ::: "memory");
        else             asm volatile("s_waitcnt vmcnt(4)" ::: "memory");
        __builtin_amdgcn_s_barrier();                 // tile t resident

        const int cur = t & 1;
        bf16x8 af[4][2], bfr[2][2];
#pragma unroll
        for (int m = 0; m < 4; ++m) {
            const int row = wm * 64 + m * 16 + lrow;
#pragma unroll
            for (int kk = 0; kk < 2; ++kk) {
                const int slot = (kk * 4 + kgrp) ^ (lrow & 7);   // 0-conflict involution (R3)
                af[m][kk] = *reinterpret_cast<const bf16x8*>(&lds[cur][0][row * 64 + slot * 8]);
            }
        }
#pragma unroll
        for (int n = 0; n < 2; ++n) {
            const int row = wn * 32 + n * 16 + lrow;
#pragma unroll
            for (int kk = 0; kk < 2; ++kk) {
                const int slot = (kk * 4 + kgrp) ^ (lrow & 7);
                bfr[n][kk] = *reinterpret_cast<const bf16x8*>(&lds[cur][1][row * 64 + slot * 8]);
            }
        }
        asm volatile("s_waitcnt lgkmcnt(0)" ::: "memory");   // all my buf[cur] reads done
        __builtin_amdgcn_s_barrier();                        // all waves done with buf[cur]

        if (t + 2 < NT) stage(t + 2, cur);                   // safe overwrite, flies under MFMA

        __builtin_amdgcn_s_setprio(1);
#pragma unroll
        for (int kk = 0; kk < 2; ++kk)
#pragma unroll
            for (int m = 0; m < 4; ++m)
#pragma unroll
                for (int n = 0; n < 2; ++n)
                    acc[m][n] = __builtin_amdgcn_mfma_f32_16x16x32_bf16(af[m][kk], bfr[n][kk], acc[m][n], 0, 0, 0);
        __builtin_amdgcn_s_setprio(0);
    }

    // epilogue: C/D layout col = lane&15, row = (lane>>4)*4 + reg
    float* Cz = (MODE == 3) ? C + (size_t)blockIdx.z * M * N : C;
#pragma unroll
    for (int m = 0; m < 4; ++m) {
        const int row = rowBase + wm * 64 + m * 16 + kgrp * 4;
#pragma unroll
        for (int n = 0; n < 2; ++n) {
            const int col = colBase + wn * 32 + n * 16 + lrow;
#pragma unroll
            for (int r = 0; r < 4; ++r) {
                float v = acc[m][n][r] + bv[n];
                if (MODE == 1) v = (v > 20.f) ? v : log1pf(expf(v));
                Cz[(size_t)(row + r) * N + col] = v;
            }
        }
    }
}

// ---------- out = part0 + part1 + bias (split-K reduce) ----------
__global__ __launch_bounds__(256) void reduce_bias(
    const float* __restrict__ part, const float* __restrict__ bias,
    float* __restrict__ out)
{
    const int i = blockIdx.x * blockDim.x + threadIdx.x;     // float4 index
    const int n4 = M * DM / 4;
    if (i >= n4) return;
    float4 a = reinterpret_cast<const float4*>(part)[i];
    float4 b = reinterpret_cast<const float4*>(part + (size_t)M * DM)[i];
    float4 bb = *reinterpret_cast<const float4*>(&bias[(i * 4) % DM]);
    float4 r;
    r.x = a.x + b.x + bb.x; r.y = a.y + b.y + bb.y;
    r.z = a.z + b.z + bb.z; r.w = a.w + b.w + bb.w;
    reinterpret_cast<float4*>(out)[i] = r;
}

// ================= chunk-parallel selective scan =================
__global__ __launch_bounds__(64) void scan_p1(
    const float* __restrict__ dt, const float* __restrict__ x,
    const float* __restrict__ xdbl, const float* __restrict__ A_log,
    float* __restrict__ P, float* __restrict__ Hloc)
{
    const int tid = threadIdx.x;
    int blk = blockIdx.x;
    const int c  = blk % CH;  blk /= CH;
    const int dg = blk % (D / 64);
    const int b  = blk / (D / 64);
    const int d  = dg * 64 + tid;

    float A[Nst], h[Nst], p[Nst];
#pragma unroll
    for (int n = 0; n < Nst; ++n) {
        A[n] = -expf(A_log[(size_t)d * Nst + n]);
        h[n] = 0.f; p[n] = 1.f;
    }

    __shared__ __attribute__((aligned(16))) float sBC[T * 16];
    const float4* src = reinterpret_cast<const float4*>(xdbl + ((size_t)b * L + c * T) * 16);
#pragma unroll
    for (int i = tid; i < T * 4; i += 64)
        reinterpret_cast<float4*>(sBC)[i] = src[i];
    __syncthreads();

    const float* dt_p = dt + ((size_t)b * L + c * T) * D + d;
    const float* x_p  = x  + ((size_t)b * L + c * T) * D + d;
#pragma unroll 4
    for (int t2 = 0; t2 < T; ++t2) {
        const float dtv = dt_p[(size_t)t2 * D];
        const float xv  = x_p[(size_t)t2 * D];
        const float dtx = dtv * xv;
        const float* bc = &sBC[t2 * 16];
#pragma unroll
        for (int n = 0; n < Nst; ++n) {
            const float dA = __expf(dtv * A[n]);
            p[n] *= dA;
            h[n] = dA * h[n] + dtx * bc[n];
        }
    }
    const size_t base = ((size_t)c * Bsz * D + (size_t)b * D + d) * Nst;
#pragma unroll
    for (int n = 0; n < Nst; ++n) { P[base + n] = p[n]; Hloc[base + n] = h[n]; }
}

__global__ __launch_bounds__(256) void scan_p2(
    const float* __restrict__ P, const float* __restrict__ Hloc,
    float* __restrict__ Hstart)
{
    const int id = blockIdx.x * blockDim.x + threadIdx.x;
    if (id >= BDN) return;
    float h = 0.f;
    for (int c = 0; c < CH; ++c) {
        const size_t o = (size_t)c * BDN + id;
        Hstart[o] = h;
        h = P[o] * h + Hloc[o];
    }
}

__global__ __launch_bounds__(64) void scan_p3(
    const float* __restrict__ dt, const float* __restrict__ x,
    const float* __restrict__ xdbl, const float* __restrict__ A_log,
    const float* __restrict__ Hstart, __bf16* __restrict__ y_bf)
{
    const int tid = threadIdx.x;
    int blk = blockIdx.x;
    const int c  = blk % CH;  blk /= CH;
    const int dg = blk % (D / 64);
    const int b  = blk / (D / 64);
    const int d  = dg * 64 + tid;

    float A[Nst], h[Nst];
    const size_t hbase = ((size_t)c * Bsz * D + (size_t)b * D + d) * Nst;
#pragma unroll
    for (int n = 0; n < Nst; ++n) {
        A[n] = -expf(A_log[(size_t)d * Nst + n]);
        h[n] = Hstart[hbase + n];
    }

    __shared__ __attribute__((aligned(16))) float sBC[T * 16];
    const float4* src = reinterpret_cast<const float4*>(xdbl + ((size_t)b * L + c * T) * 16);
#pragma unroll
    for (int i = tid; i < T * 4; i += 64)
        reinterpret_cast<float4*>(sBC)[i] = src[i];
    __syncthreads();

    const float* dt_p = dt + ((size_t)b * L + c * T) * D + d;
    const float* x_p  = x  + ((size_t)b * L + c * T) * D + d;
    __bf16*      y_p  = y_bf + ((size_t)b * L + c * T) * D + d;
#pragma unroll 4
    for (int t2 = 0; t2 < T; ++t2) {
        const float dtv = dt_p[(size_t)t2 * D];
        const float xv  = x_p[(size_t)t2 * D];
        const float dtx = dtv * xv;
        const float* bc = &sBC[t2 * 16];
        float y = 0.f;
#pragma unroll
        for (int n = 0; n < Nst; ++n) {
            const float dA = __expf(dtv * A[n]);
            h[n] = dA * h[n] + dtx * bc[n];
            y = fmaf(h[n], bc[8 + n], y);
        }
        y_p[(size_t)t2 * D] = (__bf16)y;
    }
}

extern "C" void kernel_launch(void* const* d_in, const int* in_sizes, int n_in,
                              void* d_out, int out_size, void* d_ws, size_t ws_size,
                              hipStream_t stream) {
    const float* x     = (const float*)d_in[0];
    const float* A_log = (const float*)d_in[1];
    const float* xpw   = (const float*)d_in[2];
    const float* xpb   = (const float*)d_in[3];
    const float* dtw   = (const float*)d_in[4];
    const float* dtb   = (const float*)d_in[5];
    const float* ow    = (const float*)d_in[6];
    const float* ob    = (const float*)d_in[7];
    float* out = (float*)d_out;

    char* ws = (char*)d_ws;
    __bf16* x_bf   = (__bf16*)(ws);                 // 16,777,216 B (dead after dt-GEMM)
    __bf16* dtw_bf = (__bf16*)(ws + 16777216);      //  8,388,608 B (dead after dt-GEMM)
    __bf16* ow_bf  = (__bf16*)(ws + 25165824);      //  4,194,304 B (live until out-GEMM)
    float*  xdbl   = (float* )(ws + 29360128);      //    262,144 B
    float*  dtbuf  = (float* )(ws + 29622272);      // 33,554,432 B (dead after scan_p3)
    __bf16* y_bf   = (__bf16*)(ws + 63176704);      // 16,777,216 B
    // scan scratch overlays the dead bf16 operand copies:
    float*  P      = (float*)(ws);                  // over x_bf lo
    float*  Hloc   = (float*)(ws + 8388608);        // over x_bf hi
    float*  Hstart = (float*)(ws + 16777216);       // over dtw_bf
    // split-K partials overlay dead dtbuf (2 * 16 MB = 32 MB <= 33.5 MB):
    float*  Cpart  = (float*)(ws + 29622272);

    // 1) bf16 weight copies (single fused launch)
    const int n4a = D * D / 4, n4b = DM * D / 4;
    cvt2_f32_bf16<<<(n4a + n4b + 255) / 256, 256, 0, stream>>>(dtw, dtw_bf, n4a, ow, ow_bf, n4b);

    // 2) B_t / C_t gates (exact f32) + fused x->bf16 emission
    xdbl_kernel<<<M / 16, 256, 0, stream>>>(x, xpw, xpb, xdbl, x_bf);

    // 3) dt = softplus(x @ dtw^T + dtb)   — XCD-swizzled
    gemm_bt<1, 1><<<dim3(D / 128, M / 128, 1), 512, 0, stream>>>(x_bf, dtw_bf, dtb, dtbuf, D, D, D);

    // 4) chunk-parallel selective scan -> y (bf16)
    const int scan_blocks = Bsz * (D / 64) * CH;    // 4096
    scan_p1<<<scan_blocks, 64, 0, stream>>>(dtbuf, x, xdbl, A_log, P, Hloc);
    scan_p2<<<(BDN + 255) / 256, 256, 0, stream>>>(P, Hloc, Hstart);
    scan_p3<<<scan_blocks, 64, 0, stream>>>(dtbuf, x, xdbl, A_log, Hstart, y_bf);

    // 5) out = y @ ow^T + ob — split-K=2 partials (no atomics) + reduce
    gemm_bt<3, 1><<<dim3(DM / 128, M / 128, 2), 512, 0, stream>>>(y_bf, ow_bf, ob, Cpart, DM, D, D / 2);
    reduce_bias<<<(M * DM / 4 + 255) / 256, 256, 0, stream>>>(Cpart, ob, out);
}